// Round 10
// baseline (1935.673 us; speedup 1.0000x reference)
//
#include <hip/hip_runtime.h>
#include <cstdint>

#define NB 256
#define NT 128
#define NS 128
#define NH 256
#define NTHR 1024
#define NWG  256
#define NGRP 128

// ws layout in uint32 words
#define HC_OFF  0        // [2 par][128 group][2 b][256 u] = 131072 words (f16x2 h,c)
#define CNT_OFF 131072   // [128 group][16] counters

typedef _Float16 f16;
typedef _Float16 f16x2 __attribute__((ext_vector_type(2)));
typedef _Float16 f16x8 __attribute__((ext_vector_type(8)));
typedef float    f32x4 __attribute__((ext_vector_type(4)));

#define SW 528   // wahp row stride in f16
#define SH 528   // hcp row stride in f16
#define SA 136   // act row stride in f16

__device__ __forceinline__ f16x2 pk(float a, float b) {
  f16x2 r; r.x = (f16)a; r.y = (f16)b; return r;
}
__device__ __forceinline__ f16x8 pack8(const float* s) {
  float4 v0 = *(const float4*)s, v1 = *(const float4*)(s + 4);
  f16x8 r;
  r[0] = (f16)v0.x; r[1] = (f16)v0.y; r[2] = (f16)v0.z; r[3] = (f16)v0.w;
  r[4] = (f16)v1.x; r[5] = (f16)v1.y; r[6] = (f16)v1.z; r[7] = (f16)v1.w;
  return r;
}
__device__ __forceinline__ void awr(uint32_t* p, uint32_t v) {
  __hip_atomic_store(p, v, __ATOMIC_RELAXED, __HIP_MEMORY_SCOPE_AGENT);
}
__device__ __forceinline__ uint32_t ard(uint32_t* p) {
  return __hip_atomic_load(p, __ATOMIC_RELAXED, __HIP_MEMORY_SCOPE_AGENT);
}
__device__ __forceinline__ void cinc(uint32_t* p) {
  __hip_atomic_fetch_add(p, 1u, __ATOMIC_RELAXED, __HIP_MEMORY_SCOPE_AGENT);
}
__device__ __forceinline__ void cwait(uint32_t* p, uint32_t tgt) {
  while (ard(p) < tgt) __builtin_amdgcn_s_sleep(1);
}

struct __align__(16) Sm {
  f16   wahp[128 * SW];    // 135168 B  W_ah f16 [t'][512 k]
  f16   hcp[3 * SH];       // 3168 B    [b0|b1|zero][h(0:256)|c(256:512)]
  f16   act[3 * SA];       // 816 B     [b0|b1|zero][wx 0:128]
  float PW[2 * 128 * 2];   // 2048 B    [b][t'] {P, 2*W_a[t']}  (.y static)
  float sp[4][2][128];     // 4096 B    score t'-partials
  float gacc[512][2];      // 4096 B    gate sums [lr][b]
  float gbias[512];        // 2048
  float cbuf[128 * 2];     // 1024      [ul][b]
  float bah[128];          // 512
};

__global__ void enc_init(uint32_t* ws) {
  int i = blockIdx.x * blockDim.x + threadIdx.x;
  if (i < 65536) ws[HC_OFF + i] = 0u;     // zero h,c parity 0
  if (i < 2048)  ws[CNT_OFF + i] = 0u;    // zero counters
}

__global__ __launch_bounds__(NTHR, 4) void enc_main(
    const float* __restrict__ x,    const float* __restrict__ W_ah,
    const float* __restrict__ b_ah, const float* __restrict__ W_ai,
    const float* __restrict__ b_ai, const float* __restrict__ W_a,
    const float* __restrict__ b_a,  const float* __restrict__ W_ih,
    const float* __restrict__ W_hh, const float* __restrict__ b_ih,
    const float* __restrict__ b_hh, float* __restrict__ out_iw,
    float* __restrict__ out_ie,     uint32_t* __restrict__ ws)
{
  __shared__ Sm sm;
  const int tid  = threadIdx.x;
  const int wg   = blockIdx.x;
  const int xcd  = wg & 7, slot = wg >> 3;
  const int g    = xcd * 16 + (slot >> 1);  // group 0..127 (partner = wg^8, co-XCD heuristic)
  const int gid  = slot & 1;                // member 0..1
  const int b0   = g * 2;
  const int u0   = gid * 128;               // own 128 hidden units
  const int pu0  = 128 - u0;                // partner's units

  const int wv = tid >> 6, ln = tid & 63;
  const int bn = ln & 15, kq = ln >> 4;
  const int br2 = (bn < 2) ? bn : 2;        // batch row w/ zero pad

  uint32_t* cnt = ws + CNT_OFF + (size_t)g * 16;

  // ---- persistent gate-weight B-fragments: wave wv owns local rows wv*32..+31 ----
  // local row lr -> gate (lr>>7), unit u0 + (lr&127)
  f16x8 wfrag[2][12];
  #pragma unroll
  for (int s = 0; s < 2; ++s) {
    const int lr = wv * 32 + s * 16 + bn;
    const int grow = (lr >> 7) * 256 + u0 + (lr & 127);
    #pragma unroll
    for (int kk = 0; kk < 4; ++kk)
      wfrag[s][kk] = pack8(W_ih + (size_t)grow * NS + kk * 32 + kq * 8);
    #pragma unroll
    for (int kk = 4; kk < 12; ++kk)
      wfrag[s][kk] = pack8(W_hh + (size_t)grow * NH + (kk - 4) * 32 + kq * 8);
  }

  // ---- stage W_ah into LDS f16 ----
  #pragma unroll
  for (int i = 0; i < 8; ++i) {
    int idx = i * NTHR + tid;          // 8192 chunks of 8 f16
    int r = idx >> 6, c = idx & 63;
    f16x8 v = pack8(W_ah + (size_t)r * 512 + c * 8);
    *(f16x8*)&sm.wahp[(size_t)r * SW + c * 8] = v;
  }
  if (tid < 512) {
    int grow = (tid >> 7) * 256 + u0 + (tid & 127);
    sm.gbias[tid] = b_ih[grow] + b_hh[grow];
  }
  if (tid < 256) {
    sm.cbuf[tid] = 0.f;
    int b = tid >> 7, tp = tid & 127;
    sm.PW[(b * 128 + tp) * 2 + 1] = 2.f * W_a[tp];   // static .y
  }
  if (tid < 128) sm.bah[tid] = b_ah[tid];
  for (int i = tid; i < 3 * SH; i += NTHR) sm.hcp[i] = (f16)0.f;
  for (int i = tid; i < 3 * SA; i += NTHR) sm.act[i] = (f16)0.f;

  // ---- per-thread E (exp(2*ipart)) for (b=(tid>>7)&1, n=tid&127) ----
  const int n_s = tid & 127, b_s = (tid >> 7) & 1, ts_s = tid >> 8;
  float ev;
  {
    const float* xb = x + (size_t)(b0 + b_s) * NT * NS;
    float a = 0.f;
    #pragma unroll 4
    for (int t = 0; t < NT; ++t) a = fmaf(xb[(size_t)t * NS + n_s], W_ai[t], a);
    ev = __expf(2.f * (a + b_ai[0]));
  }
  float S0;
  { float s = b_a[0]; for (int i = 0; i < 128; ++i) s += W_a[i]; S0 = s; }

  __syncthreads();

  for (int t = 0; t < NT; ++t) {
    const int par = t & 1, par2 = 1 - par;
    // ---- prefetch x_t for softmax (waves 0-1, batch = wv) ----
    float xv0 = 0.f, xv1 = 0.f;
    if (wv < 2) {
      const float* xr = x + ((size_t)(b0 + wv) * NT + t) * NS;
      xv0 = xr[ln]; xv1 = xr[ln + 64];
    }
    if (t > 0) {
      // ---- wait partner (tid0 relaxed poll), then read partner h,c ----
      if (tid == 0) cwait(cnt, 2u * (uint32_t)t);
      __syncthreads();                                   // B1
      if (tid < 256) {
        int b = tid >> 7, ul = tid & 127;
        uint32_t v = ard(ws + HC_OFF + (((size_t)par * NGRP + g) * 2 + b) * 256 + pu0 + ul);
        f16x2 pv = __builtin_bit_cast(f16x2, v);
        sm.hcp[b * SH + pu0 + ul] = pv.x;
        sm.hcp[b * SH + 256 + pu0 + ul] = pv.y;
      }
      __syncthreads();                                   // B2
    }
    // ---- hpart MFMA full-K: waves 0-7, m-tile = wv ----
    if (wv < 8) {
      f32x4 acc = {0.f, 0.f, 0.f, 0.f};
      #pragma unroll
      for (int kk = 0; kk < 16; ++kk) {
        f16x8 a = *(const f16x8*)&sm.wahp[(size_t)(wv * 16 + bn) * SW + kk * 32 + kq * 8];
        f16x8 b = *(const f16x8*)&sm.hcp[(size_t)br2 * SH + kk * 32 + kq * 8];
        acc = __builtin_amdgcn_mfma_f32_16x16x32_f16(a, b, acc, 0, 0, 0);
      }
      if (bn < 2) {
        #pragma unroll
        for (int r = 0; r < 4; ++r) {
          int tp = wv * 16 + kq * 4 + r;
          sm.PW[(bn * 128 + tp) * 2] = __expf(2.f * (acc[r] + sm.bah[tp]));
        }
      }
    }
    __syncthreads();                                     // B3
    // ---- score: (ts, b, n) threads, 32 t' terms via 16 rcp-paired iters ----
    {
      float s = 0.f;
      #pragma unroll 8
      for (int i = 0; i < 16; ++i) {
        float4 rd = *(const float4*)&sm.PW[(b_s * 128 + ts_s * 32 + 2 * i) * 2];
        float d1 = fmaf(rd.x, ev, 1.f);
        float d2 = fmaf(rd.z, ev, 1.f);
        float num = fmaf(rd.w, d1, rd.y * d2);
        s = fmaf(num, __builtin_amdgcn_rcpf(d1 * d2), s);
      }
      sm.sp[ts_s][b_s][n_s] = s;
    }
    __syncthreads();                                     // B4
    // ---- softmax + wx (waves 0-1, batch = wv) ----
    if (wv < 2) {
      float sA = S0 - (sm.sp[0][wv][ln] + sm.sp[1][wv][ln] + sm.sp[2][wv][ln] + sm.sp[3][wv][ln]);
      float sB = S0 - (sm.sp[0][wv][ln + 64] + sm.sp[1][wv][ln + 64] + sm.sp[2][wv][ln + 64] + sm.sp[3][wv][ln + 64]);
      float m = fmaxf(sA, sB);
      #pragma unroll
      for (int o = 32; o; o >>= 1) m = fmaxf(m, __shfl_xor(m, o));
      float eA = __expf(sA - m), eB = __expf(sB - m);
      float ss = eA + eB;
      #pragma unroll
      for (int o = 32; o; o >>= 1) ss += __shfl_xor(ss, o);
      float rs = 1.f / ss;
      float wxA = eA * rs * xv0, wxB = eB * rs * xv1;
      sm.act[wv * SA + ln] = (f16)wxA;
      sm.act[wv * SA + ln + 64] = (f16)wxB;
      if (gid == wv) {
        float* ow = out_iw + ((size_t)(b0 + wv) * NT + t) * NS;
        ow[ln] = wxA; ow[ln + 64] = wxB;
      }
    }
    __syncthreads();                                     // B5
    // ---- gates MFMA: 2 row-sets x 12 K-steps, weights in registers ----
    {
      #pragma unroll
      for (int s = 0; s < 2; ++s) {
        f32x4 acc = {0.f, 0.f, 0.f, 0.f};
        #pragma unroll
        for (int kk = 0; kk < 4; ++kk) {
          f16x8 a = *(const f16x8*)&sm.act[(size_t)br2 * SA + kk * 32 + kq * 8];
          acc = __builtin_amdgcn_mfma_f32_16x16x32_f16(a, wfrag[s][kk], acc, 0, 0, 0);
        }
        #pragma unroll
        for (int kk = 4; kk < 12; ++kk) {
          f16x8 a = *(const f16x8*)&sm.hcp[(size_t)br2 * SH + (kk - 4) * 32 + kq * 8];
          acc = __builtin_amdgcn_mfma_f32_16x16x32_f16(a, wfrag[s][kk], acc, 0, 0, 0);
        }
        if (ln < 16) {
          sm.gacc[wv * 32 + s * 16 + ln][0] = acc[0];
          sm.gacc[wv * 32 + s * 16 + ln][1] = acc[1];
        }
      }
    }
    __syncthreads();                                     // B6
    // ---- LSTM pointwise: own 128 units x 2 batches; write own hcp + publish ----
    if (tid < 256) {
      const int b = tid >> 7, ul = tid & 127;
      float gi = sm.gacc[ul][b]        + sm.gbias[ul];
      float gf = sm.gacc[128 + ul][b]  + sm.gbias[128 + ul];
      float gg = sm.gacc[256 + ul][b]  + sm.gbias[256 + ul];
      float go = sm.gacc[384 + ul][b]  + sm.gbias[384 + ul];
      float ii = 1.f / (1.f + __expf(-gi));
      float ff = 1.f / (1.f + __expf(-gf));
      float gt = 1.f - 2.f / (1.f + __expf(2.f * gg));
      float oo = 1.f / (1.f + __expf(-go));
      float c2 = ff * sm.cbuf[ul * 2 + b] + ii * gt;
      float h2 = oo * (1.f - 2.f / (1.f + __expf(2.f * c2)));
      sm.cbuf[ul * 2 + b] = c2;
      f16x2 pv = pk(h2, c2);
      sm.hcp[b * SH + u0 + ul] = pv.x;
      sm.hcp[b * SH + 256 + u0 + ul] = pv.y;
      out_ie[((size_t)(b0 + b) * NT + t) * NH + u0 + ul] = h2;
      awr(ws + HC_OFF + (((size_t)par2 * NGRP + g) * 2 + b) * 256 + u0 + ul,
          __builtin_bit_cast(uint32_t, pv));
    }
    __syncthreads();                                     // B7 (drains publish)
    if (tid == 0) cinc(cnt);
  }
}

extern "C" void kernel_launch(void* const* d_in, const int* in_sizes, int n_in,
                              void* d_out, int out_size, void* d_ws, size_t ws_size,
                              hipStream_t stream) {
  const float* x    = (const float*)d_in[0];
  const float* W_ah = (const float*)d_in[1];
  const float* b_ah = (const float*)d_in[2];
  const float* W_ai = (const float*)d_in[3];
  const float* b_ai = (const float*)d_in[4];
  const float* W_a  = (const float*)d_in[5];
  const float* b_a  = (const float*)d_in[6];
  const float* W_ih = (const float*)d_in[7];
  const float* W_hh = (const float*)d_in[8];
  const float* b_ih = (const float*)d_in[9];
  const float* b_hh = (const float*)d_in[10];
  float* out_iw = (float*)d_out;
  float* out_ie = (float*)d_out + (size_t)NB * NT * NS;
  uint32_t* ws = (uint32_t*)d_ws;

  hipLaunchKernelGGL(enc_init, dim3(256), dim3(256), 0, stream, ws);
  hipLaunchKernelGGL(enc_main, dim3(NWG), dim3(NTHR), 0, stream,
                     x, W_ah, b_ah, W_ai, b_ai, W_a, b_a, W_ih, W_hh, b_ih, b_hh,
                     out_iw, out_ie, ws);
}

// Round 11
// 723.394 us; speedup vs baseline: 2.6758x; 2.6758x over previous
//
#include <hip/hip_runtime.h>
#include <cstdint>

#define NB 256
#define NT 128
#define NS 128
#define NH 256
#define NTHR 1024
#define NWG  256
#define NGRP 64
#define GBAT 4      // batch elems per group
#define UPW  64     // hidden units per wg

// ws layout in uint32 words
#define HC_OFF  0        // [2 par][64 group][4 b][256 u] = 131072 words (f16x2 h,c)
#define CNT_OFF 131072   // [64 group][16] counters

typedef _Float16 f16;
typedef _Float16 f16x2 __attribute__((ext_vector_type(2)));
typedef _Float16 f16x8 __attribute__((ext_vector_type(8)));
typedef float    f32x4 __attribute__((ext_vector_type(4)));

#define SW 528   // wahp row stride in f16
#define SH 528   // hcp row stride in f16
#define SA 136   // act row stride in f16

__device__ __forceinline__ f16x2 pk(float a, float b) {
  f16x2 r; r.x = (f16)a; r.y = (f16)b; return r;
}
__device__ __forceinline__ f16x8 pack8(const float* s) {
  float4 v0 = *(const float4*)s, v1 = *(const float4*)(s + 4);
  f16x8 r;
  r[0] = (f16)v0.x; r[1] = (f16)v0.y; r[2] = (f16)v0.z; r[3] = (f16)v0.w;
  r[4] = (f16)v1.x; r[5] = (f16)v1.y; r[6] = (f16)v1.z; r[7] = (f16)v1.w;
  return r;
}
__device__ __forceinline__ void awr(uint32_t* p, uint32_t v) {
  __hip_atomic_store(p, v, __ATOMIC_RELAXED, __HIP_MEMORY_SCOPE_AGENT);
}
__device__ __forceinline__ uint32_t ard(uint32_t* p) {
  return __hip_atomic_load(p, __ATOMIC_RELAXED, __HIP_MEMORY_SCOPE_AGENT);
}
__device__ __forceinline__ void cinc(uint32_t* p) {
  __hip_atomic_fetch_add(p, 1u, __ATOMIC_RELAXED, __HIP_MEMORY_SCOPE_AGENT);
}
__device__ __forceinline__ void cwait(uint32_t* p, uint32_t tgt) {
  while (ard(p) < tgt) __builtin_amdgcn_s_sleep(1);
}

struct __align__(16) Sm {
  f16   wahp[128 * SW];    // 135168 B  W_ah f16 [t'][512 k]
  f16   hcp[5 * SH];       // 5280 B    [b0..b3|zero][h(0:256)|c(256:512)]
  f16   act[5 * SA];       // 1360 B    [b0..b3|zero][wx 0:128]
  float PW[4 * 128 * 2];   // 4096 B    [b][t'] {P, 2*W_a[t']}  (.y static)
  float sp[2][4][128];     // 4096 B    score t'-half partials
  float gacc[256][4];      // 4096 B    gate sums [lr][b]
  float gbias[256];        // 1024
  float cbuf[64][4];       // 1024      [ul][b]
  float bah[128];          // 512
};

__global__ void enc_init(uint32_t* ws) {
  int i = blockIdx.x * blockDim.x + threadIdx.x;
  if (i < 65536) ws[HC_OFF + i] = 0u;
  if (i < 1024)  ws[CNT_OFF + i] = 0u;
}

__global__ __launch_bounds__(NTHR, 4) void enc_main(
    const float* __restrict__ x,    const float* __restrict__ W_ah,
    const float* __restrict__ b_ah, const float* __restrict__ W_ai,
    const float* __restrict__ b_ai, const float* __restrict__ W_a,
    const float* __restrict__ b_a,  const float* __restrict__ W_ih,
    const float* __restrict__ W_hh, const float* __restrict__ b_ih,
    const float* __restrict__ b_hh, float* __restrict__ out_iw,
    float* __restrict__ out_ie,     uint32_t* __restrict__ ws)
{
  __shared__ Sm sm;
  const int tid  = threadIdx.x;
  const int wg   = blockIdx.x;
  const int xcd  = wg & 7, slot = wg >> 3;
  const int g    = xcd * 8 + (slot >> 2);   // group 0..63 (co-XCD heuristic, perf-only)
  const int gid  = slot & 3;                // member 0..3
  const int b0   = g * GBAT;
  const int u0   = gid * UPW;

  const int wv = tid >> 6, ln = tid & 63;
  const int bn = ln & 15, kq = ln >> 4;
  const int br = (bn < 4) ? bn : 4;         // batch row w/ zero pad

  uint32_t* cnt = ws + CNT_OFF + (size_t)g * 16;

  // ---- persistent gate-weight B-fragments: wave wv owns local rows wv*16..+15 ----
  // lr -> gate (lr>>6), unit u0 + (lr&63).  12 frags = 48 VGPR (proven no-remat).
  f16x8 wfrag[12];
  {
    const int lr = wv * 16 + bn;
    const int grow = (lr >> 6) * 256 + u0 + (lr & 63);
    #pragma unroll
    for (int kk = 0; kk < 4; ++kk)
      wfrag[kk] = pack8(W_ih + (size_t)grow * NS + kk * 32 + kq * 8);
    #pragma unroll
    for (int kk = 4; kk < 12; ++kk)
      wfrag[kk] = pack8(W_hh + (size_t)grow * NH + (kk - 4) * 32 + kq * 8);
  }

  // ---- stage W_ah into LDS f16 ----
  #pragma unroll
  for (int i = 0; i < 8; ++i) {
    int idx = i * NTHR + tid;          // 8192 chunks of 8 f16
    int r = idx >> 6, c = idx & 63;
    f16x8 v = pack8(W_ah + (size_t)r * 512 + c * 8);
    *(f16x8*)&sm.wahp[(size_t)r * SW + c * 8] = v;
  }
  if (tid < 256) {
    int grow = (tid >> 6) * 256 + u0 + (tid & 63);
    sm.gbias[tid] = b_ih[grow] + b_hh[grow];
    sm.cbuf[tid & 63][tid >> 6] = 0.f;
  }
  if (tid < 512) {
    int b = tid >> 7, tp = tid & 127;
    sm.PW[(b * 128 + tp) * 2 + 1] = 2.f * W_a[tp];   // static .y
  }
  if (tid < 128) sm.bah[tid] = b_ah[tid];
  for (int i = tid; i < 5 * SH; i += NTHR) sm.hcp[i] = (f16)0.f;
  for (int i = tid; i < 5 * SA; i += NTHR) sm.act[i] = (f16)0.f;

  // ---- per-thread E (exp(2*ipart)) at (n=tid&127, b=(tid>>7)&3) ----
  const int n_s = tid & 127, b_s = (tid >> 7) & 3, ts_s = tid >> 9;
  float ev;
  {
    const float* xb = x + (size_t)(b0 + b_s) * NT * NS;
    float a = 0.f;
    #pragma unroll 4
    for (int t = 0; t < NT; ++t) a = fmaf(xb[(size_t)t * NS + n_s], W_ai[t], a);
    ev = __expf(2.f * (a + b_ai[0]));
  }
  float S0;
  { float s = b_a[0]; for (int i = 0; i < 128; ++i) s += W_a[i]; S0 = s; }

  __syncthreads();

  for (int t = 0; t < NT; ++t) {
    const int par = t & 1, par2 = 1 - par;
    // ---- prefetch x_t for softmax (waves 0-3, batch = wv) ----
    float xv0 = 0.f, xv1 = 0.f;
    if (wv < 4) {
      const float* xr = x + ((size_t)(b0 + wv) * NT + t) * NS;
      xv0 = xr[ln]; xv1 = xr[ln + 64];
    }
    if (t > 0) {
      // ---- single group sync: tid0 relaxed poll, barrier fan-out ----
      if (tid == 0) cwait(cnt, 4u * (uint32_t)t);
      __syncthreads();                                   // B1
      // ---- read partner h,c (768 words; own 64-unit slice already in hcp) ----
      {
        int b = tid >> 8, u = tid & 255;
        if ((u >> 6) != gid) {
          uint32_t v = ard(ws + HC_OFF + (((size_t)par * NGRP + g) * 4 + b) * 256 + u);
          f16x2 pv = __builtin_bit_cast(f16x2, v);
          sm.hcp[b * SH + u] = pv.x;
          sm.hcp[b * SH + 256 + u] = pv.y;
        }
      }
      __syncthreads();                                   // B2
    }
    // ---- hpart MFMA full-K (waves 0-7, m-tile = wv): P -> PW.x ----
    if (wv < 8) {
      f32x4 acc = {0.f, 0.f, 0.f, 0.f};
      #pragma unroll
      for (int kk = 0; kk < 16; ++kk) {
        f16x8 a = *(const f16x8*)&sm.wahp[(size_t)(wv * 16 + bn) * SW + kk * 32 + kq * 8];
        f16x8 b = *(const f16x8*)&sm.hcp[(size_t)br * SH + kk * 32 + kq * 8];
        acc = __builtin_amdgcn_mfma_f32_16x16x32_f16(a, b, acc, 0, 0, 0);
      }
      if (bn < 4) {
        #pragma unroll
        for (int r = 0; r < 4; ++r) {
          int tp = wv * 16 + kq * 4 + r;
          sm.PW[(bn * 128 + tp) * 2] = __expf(2.f * (acc[r] + sm.bah[tp]));
        }
      }
    }
    __syncthreads();                                     // B3
    // ---- score: (ts, b, n) threads; 64 t' terms via 32 rcp-paired iters ----
    {
      float s = 0.f;
      #pragma unroll 8
      for (int i = 0; i < 32; ++i) {
        float4 rd = *(const float4*)&sm.PW[(b_s * 128 + ts_s * 64 + 2 * i) * 2];
        float d1 = fmaf(rd.x, ev, 1.f);
        float d2 = fmaf(rd.z, ev, 1.f);
        float num = fmaf(rd.w, d1, rd.y * d2);
        s = fmaf(num, __builtin_amdgcn_rcpf(d1 * d2), s);
      }
      sm.sp[ts_s][b_s][n_s] = s;
    }
    __syncthreads();                                     // B4
    // ---- softmax + wx (waves 0-3, batch = wv) ----
    if (wv < 4) {
      float sA = S0 - (sm.sp[0][wv][ln] + sm.sp[1][wv][ln]);
      float sB = S0 - (sm.sp[0][wv][ln + 64] + sm.sp[1][wv][ln + 64]);
      float m = fmaxf(sA, sB);
      #pragma unroll
      for (int o = 32; o; o >>= 1) m = fmaxf(m, __shfl_xor(m, o));
      float eA = __expf(sA - m), eB = __expf(sB - m);
      float ss = eA + eB;
      #pragma unroll
      for (int o = 32; o; o >>= 1) ss += __shfl_xor(ss, o);
      float rs = 1.f / ss;
      float wxA = eA * rs * xv0, wxB = eB * rs * xv1;
      sm.act[wv * SA + ln] = (f16)wxA;
      sm.act[wv * SA + ln + 64] = (f16)wxB;
      if (gid == wv) {
        float* ow = out_iw + ((size_t)(b0 + wv) * NT + t) * NS;
        ow[ln] = wxA; ow[ln + 64] = wxB;
      }
    }
    __syncthreads();                                     // B5
    // ---- gates MFMA: wx from act, h direct from hcp; weights in registers ----
    {
      f32x4 acc = {0.f, 0.f, 0.f, 0.f};
      #pragma unroll
      for (int kk = 0; kk < 4; ++kk) {
        f16x8 a = *(const f16x8*)&sm.act[(size_t)br * SA + kk * 32 + kq * 8];
        acc = __builtin_amdgcn_mfma_f32_16x16x32_f16(a, wfrag[kk], acc, 0, 0, 0);
      }
      #pragma unroll
      for (int kk = 4; kk < 12; ++kk) {
        f16x8 a = *(const f16x8*)&sm.hcp[(size_t)br * SH + (kk - 4) * 32 + kq * 8];
        acc = __builtin_amdgcn_mfma_f32_16x16x32_f16(a, wfrag[kk], acc, 0, 0, 0);
      }
      if (ln < 16)
        *(f32x4*)&sm.gacc[wv * 16 + ln][0] = acc;
    }
    __syncthreads();                                     // B6
    // ---- LSTM pointwise: own 64 units x 4 batches; write hcp + publish ----
    if (tid < 256) {
      const int b = tid >> 6, ul = tid & 63;
      float gi = sm.gacc[ul][b]        + sm.gbias[ul];
      float gf = sm.gacc[64 + ul][b]   + sm.gbias[64 + ul];
      float gg = sm.gacc[128 + ul][b]  + sm.gbias[128 + ul];
      float go = sm.gacc[192 + ul][b]  + sm.gbias[192 + ul];
      float ii = 1.f / (1.f + __expf(-gi));
      float ff = 1.f / (1.f + __expf(-gf));
      float gt = 1.f - 2.f / (1.f + __expf(2.f * gg));
      float oo = 1.f / (1.f + __expf(-go));
      float c2 = ff * sm.cbuf[ul][b] + ii * gt;
      float h2 = oo * (1.f - 2.f / (1.f + __expf(2.f * c2)));
      sm.cbuf[ul][b] = c2;
      f16x2 pv = pk(h2, c2);
      sm.hcp[b * SH + u0 + ul] = pv.x;
      sm.hcp[b * SH + 256 + u0 + ul] = pv.y;
      out_ie[((size_t)(b0 + b) * NT + t) * NH + u0 + ul] = h2;
      awr(ws + HC_OFF + (((size_t)par2 * NGRP + g) * 4 + b) * 256 + u0 + ul,
          __builtin_bit_cast(uint32_t, pv));
    }
    __syncthreads();                                     // B7 (drains publish)
    if (tid == 0) cinc(cnt);
  }
}

extern "C" void kernel_launch(void* const* d_in, const int* in_sizes, int n_in,
                              void* d_out, int out_size, void* d_ws, size_t ws_size,
                              hipStream_t stream) {
  const float* x    = (const float*)d_in[0];
  const float* W_ah = (const float*)d_in[1];
  const float* b_ah = (const float*)d_in[2];
  const float* W_ai = (const float*)d_in[3];
  const float* b_ai = (const float*)d_in[4];
  const float* W_a  = (const float*)d_in[5];
  const float* b_a  = (const float*)d_in[6];
  const float* W_ih = (const float*)d_in[7];
  const float* W_hh = (const float*)d_in[8];
  const float* b_ih = (const float*)d_in[9];
  const float* b_hh = (const float*)d_in[10];
  float* out_iw = (float*)d_out;
  float* out_ie = (float*)d_out + (size_t)NB * NT * NS;
  uint32_t* ws = (uint32_t*)d_ws;

  hipLaunchKernelGGL(enc_init, dim3(256), dim3(256), 0, stream, ws);
  hipLaunchKernelGGL(enc_main, dim3(NWG), dim3(NTHR), 0, stream,
                     x, W_ah, b_ah, W_ai, b_ai, W_a, b_a, W_ih, W_hh, b_ih, b_hh,
                     out_iw, out_ie, ws);
}